// Round 2
// baseline (590.775 us; speedup 1.0000x reference)
//
#include <hip/hip_runtime.h>
#include <stdint.h>

// HungarianMatcher on MI355X — round 6: strip pack to its BW floor.
// Budget model: ~480 us of the 590 is harness workspace re-poison fill
// (3x 1.07 GB @ 6.7 TB/s, visible as fillBufferAligned in rocprof top-5);
// controllable slice ~110 us = pack(~26) + mfma(~35, BW-bound at 210 MB
// floor) + hungarian(~19, latency-bound) + memset/gaps.
// This round:
//   * tm_counts via MFMA: padded A-row 100 (was a dup of row 99) becomes a
//     row of bf16 ones -> Cpm[100][t] = sum_p tm[t][p], exact integers in
//     f32 accum. pack_kernel loses its 32-iter ballot loop (~200 VALU/thr)
//     and becomes a pure threshold-copy at the 134 MB HBM floor.
//   * memset fused into pack (first 59136 threads zero accd+accs) -> one
//     fewer dispatch in the graph.
//   * bpair multiply strength-reduced to shifts (full-rate VALU).

#define BATCH 8
#define NQ    100
#define NT    32
#define HWP   65536      // 256*256
#define NCLS  81
#define BIGV  1.0e6
#define MPAD  112        // 7*16
#define MTILES 7
#define KSPLIT 16
#define KC (HWP / KSPLIT)   // 4096 px per block
#define KW (KC / 4)         // 1024 px per wave
#define NITER (KW / 64)     // 16 k-iters of 64 px
#define NZFLOAT 59136       // (2*BATCH*MPAD*32 + 2*BATCH*MPAD) floats

typedef __attribute__((ext_vector_type(8))) short short8;
typedef __attribute__((ext_vector_type(4))) float f32x4;

union FragU { short8 s; uint32_t w[4]; };

__device__ inline uint32_t cvt_pk_bf16(float lo, float hi) {  // RNE packed cvt
    uint32_t r;
    asm("v_cvt_pk_bf16_f32 %0, %1, %2" : "=v"(r) : "v"(lo), "v"(hi));
    return r;
}

// expand bit r (lo halves) / bit r+16 (hi halves) of two packed words into
// two bf16-pair words: value 1.0 (0x3F80) or 0 per half.
// m * 0x3F80 == (m<<14) - (m<<7)  (full-rate shifts, no v_mul_lo_u32)
__device__ inline void bpair(uint32_t wlo, uint32_t whi, int r,
                             uint32_t& lofrag, uint32_t& hifrag) {
    uint32_t a = wlo >> r;
    uint32_t c = whi >> r;
    uint32_t mlo = (a & 1u) | ((c & 1u) << 16);
    uint32_t mhi = ((a >> 16) & 1u) | (((c >> 16) & 1u) << 16);
    lofrag = (mlo << 14) - (mlo << 7);
    hifrag = (mhi << 14) - (mhi << 7);
}

// -------------------------------------------------------------------------
// Pure threshold-copy: 2 output px per thread via one float4 (contiguous
// 16 B/lane), uint2 packed store. Also zeros accd/accs (replaces memset).
__global__ __launch_bounds__(256) void pack_kernel(const float* __restrict__ tmask,
                                                   uint32_t* __restrict__ packed,
                                                   float* __restrict__ zbuf) {
    int idx = blockIdx.x * 256 + threadIdx.x;   // BATCH * HWP/2 threads
    if (idx < NZFLOAT) zbuf[idx] = 0.f;         // fused accumulator clear
    int b  = idx >> 15;                         // 32768 pairs per batch
    int pp = idx & 32767;
    int y  = pp >> 7;                           // out row (in row = 2y)
    int xp = pp & 127;                          // pair: out x = 2xp, 2xp+1
    const float* base = tmask + (size_t)b * NT * 262144 + (size_t)(2 * y) * 512 + 4 * xp;
    uint32_t w0 = 0, w1 = 0;
#pragma unroll
    for (int t = 0; t < NT; ++t) {
        float4 v = *(const float4*)(base + (size_t)t * 262144);
        w0 |= (v.x > 0.5f ? 1u : 0u) << t;
        w1 |= (v.z > 0.5f ? 1u : 0u) << t;
    }
    int p0 = y * 256 + 2 * xp;
    *(uint2*)(packed + (size_t)b * HWP + p0) = make_uint2(w0, w1);
}

// -------------------------------------------------------------------------
// accd: [2][BATCH][MPAD][32] fp32 (dot_pm, dot_sig); accs: [2][BATCH][MPAD]
// Row 100 of the dot_pm accumulator carries the target-mask pixel counts
// (A-row 100 forced to bf16 ones; integer sums < 2^24 -> exact in f32).
__global__ __launch_bounds__(256) void mfma_kernel(const float* __restrict__ pmask,
                                                   const uint32_t* __restrict__ packed,
                                                   float* __restrict__ accd,
                                                   float* __restrict__ accs) {
    const int kblk = blockIdx.x;
    const int mt   = blockIdx.y;
    const int b    = blockIdx.z;
    const int tid  = threadIdx.x;
    const int wv   = tid >> 6, lane = tid & 63;
    const int m0   = mt * 16;
    const int q    = lane >> 4;    // 0..3  (k-quad)
    const int r    = lane & 15;    // 0..15 (A row / B target)

    __shared__ float Cred[8][16][32];

    const bool onesrow = (m0 + r == 100);                  // counts row
    int mrow = m0 + r; if (mrow > NQ - 1) mrow = NQ - 1;   // pad rows dup row 99
    const float* Arow = pmask + (size_t)b * NQ * HWP + (size_t)mrow * HWP;
    const uint32_t* pkb = packed + (size_t)b * HWP;
    const int kbase0 = kblk * KC + wv * KW;

    f32x4 Cpm0 = {0,0,0,0}, Cpm1 = {0,0,0,0}, Csg0 = {0,0,0,0}, Csg1 = {0,0,0,0};
    float rsp = 0.f, rsg = 0.f;

    for (int ki = 0; ki < NITER; ++ki) {
        const int kb = kbase0 + ki * 64;
        // --- direct fragment loads (no LDS) ---
        const float4 va0 = *(const float4*)(Arow + kb + q * 8);
        const float4 va1 = *(const float4*)(Arow + kb + q * 8 + 4);
        const float4 va2 = *(const float4*)(Arow + kb + 32 + q * 8);
        const float4 va3 = *(const float4*)(Arow + kb + 32 + q * 8 + 4);
        const uint4  wb0 = *(const uint4*)(pkb + kb + q * 8);
        const uint4  wb1 = *(const uint4*)(pkb + kb + q * 8 + 4);
        const uint4  wb2 = *(const uint4*)(pkb + kb + 32 + q * 8);
        const uint4  wb3 = *(const uint4*)(pkb + kb + 32 + q * 8 + 4);

        FragU a0, a1, g0, g1;
        auto proc4 = [&](const float4& v, uint32_t* aw, uint32_t* gw) {
            float sg[4];
#pragma unroll
            for (int e = 0; e < 4; ++e) {
                float pv = (&v.x)[e];
                float ax = fabsf(pv);
                float en = __expf(-ax);
                float one_en = 1.0f + en;
                float inv = __builtin_amdgcn_rcpf(one_en);
                float sig = (pv >= 0.f) ? inv : en * inv;
                float sp  = fmaxf(pv, 0.f) + __logf(one_en);
                rsp += sp; rsg += sig;
                sg[e] = sig;
            }
            aw[0] = cvt_pk_bf16(v.x, v.y);
            aw[1] = cvt_pk_bf16(v.z, v.w);
            gw[0] = cvt_pk_bf16(sg[0], sg[1]);
            gw[1] = cvt_pk_bf16(sg[2], sg[3]);
        };
        proc4(va0, &a0.w[0], &g0.w[0]);
        proc4(va1, &a0.w[2], &g0.w[2]);
        proc4(va2, &a1.w[0], &g1.w[0]);
        proc4(va3, &a1.w[2], &g1.w[2]);

        if (onesrow) {   // lane-divergent cndmask x8: A-row 100 = bf16 ones
#pragma unroll
            for (int i2 = 0; i2 < 4; ++i2) { a0.w[i2] = 0x3F803F80u; a1.w[i2] = 0x3F803F80u; }
        }

        FragU b00, b01, b10, b11;
        bpair(wb0.x, wb0.y, r, b00.w[0], b10.w[0]);
        bpair(wb0.z, wb0.w, r, b00.w[1], b10.w[1]);
        bpair(wb1.x, wb1.y, r, b00.w[2], b10.w[2]);
        bpair(wb1.z, wb1.w, r, b00.w[3], b10.w[3]);
        bpair(wb2.x, wb2.y, r, b01.w[0], b11.w[0]);
        bpair(wb2.z, wb2.w, r, b01.w[1], b11.w[1]);
        bpair(wb3.x, wb3.y, r, b01.w[2], b11.w[2]);
        bpair(wb3.z, wb3.w, r, b01.w[3], b11.w[3]);

        Cpm0 = __builtin_amdgcn_mfma_f32_16x16x32_bf16(a0.s, b00.s, Cpm0, 0, 0, 0);
        Cpm0 = __builtin_amdgcn_mfma_f32_16x16x32_bf16(a1.s, b01.s, Cpm0, 0, 0, 0);
        Cpm1 = __builtin_amdgcn_mfma_f32_16x16x32_bf16(a0.s, b10.s, Cpm1, 0, 0, 0);
        Cpm1 = __builtin_amdgcn_mfma_f32_16x16x32_bf16(a1.s, b11.s, Cpm1, 0, 0, 0);
        Csg0 = __builtin_amdgcn_mfma_f32_16x16x32_bf16(g0.s, b00.s, Csg0, 0, 0, 0);
        Csg0 = __builtin_amdgcn_mfma_f32_16x16x32_bf16(g1.s, b01.s, Csg0, 0, 0, 0);
        Csg1 = __builtin_amdgcn_mfma_f32_16x16x32_bf16(g0.s, b10.s, Csg1, 0, 0, 0);
        Csg1 = __builtin_amdgcn_mfma_f32_16x16x32_bf16(g1.s, b11.s, Csg1, 0, 0, 0);
    }

    // row sums: reduce across the 4 k-quads (lane bits 4,5) -> q==0 lanes
    rsp += __shfl_xor(rsp, 16, 64);
    rsp += __shfl_xor(rsp, 32, 64);
    rsg += __shfl_xor(rsg, 16, 64);
    rsg += __shfl_xor(rsg, 32, 64);
    if (q == 0 && m0 + r < NQ) {
        atomicAdd(&accs[(size_t)b * MPAD + m0 + r], rsp);
        atomicAdd(&accs[(size_t)(BATCH + b) * MPAD + m0 + r], rsg);
    }

    // C/D layout: col = lane&15 (target), row = (lane>>4)*4 + e (query)
#pragma unroll
    for (int e = 0; e < 4; ++e) {
        const int m = q * 4 + e;
        Cred[wv * 2 + 0][m][r]      = Cpm0[e];
        Cred[wv * 2 + 0][m][16 + r] = Cpm1[e];
        Cred[wv * 2 + 1][m][r]      = Csg0[e];
        Cred[wv * 2 + 1][m][16 + r] = Csg1[e];
    }
    __syncthreads();
    for (int idx = tid; idx < 1024; idx += 256) {
        const int type = idx >> 9, rem = idx & 511, m = rem >> 5, n = rem & 31;
        float s = Cred[0 + type][m][n] + Cred[2 + type][m][n]
                + Cred[4 + type][m][n] + Cred[6 + type][m][n];
        const int gm = m0 + m;
        if (gm < 101)   // rows 0..99 = queries, row 100 = tm counts
            atomicAdd(&accd[(size_t)(type * BATCH + b) * MPAD * 32 + (size_t)gm * 32 + n], s);
    }
}

// -------------------------------------------------------------------------
// Finalize cost matrix + exact single-wave JV Hungarian.
__global__ __launch_bounds__(64) void hungarian_kernel(const float* __restrict__ logits,
                                                       const int* __restrict__ labels,
                                                       const float* __restrict__ accd,
                                                       const float* __restrict__ accs,
                                                       int* __restrict__ out) {
    const int b = blockIdx.x;
    const int lane = threadIdx.x;

    __shared__ double Ct[NT][NQ];
    __shared__ double u[NT + 1];
    __shared__ float smx[NQ], ssm[NQ];
    __shared__ float tcs[NT];
    __shared__ int lab[NT];

    if (lane < NT) {
        tcs[lane] = accd[(size_t)b * MPAD * 32 + 100 * 32 + lane];  // MFMA-computed counts
        lab[lane] = labels[b * NT + lane];
    }
    for (int n = lane; n < NQ; n += 64) {
        const float* lg = logits + (size_t)(b * NQ + n) * NCLS;
        float mx = -1e30f;
        for (int c = 0; c < NCLS; ++c) mx = fmaxf(mx, lg[c]);
        float s = 0.f;
        for (int c = 0; c < NCLS; ++c) s += __expf(lg[c] - mx);
        smx[n] = mx; ssm[n] = s;
    }
    if (lane <= NT) u[lane] = 0.0;
    __syncthreads();
    for (int idx = lane; idx < NQ * NT; idx += 64) {
        const int t2 = idx & 31, q2 = idx >> 5;
        float dpm = accd[(size_t)b * MPAD * 32 + q2 * 32 + t2];
        float dsg = accd[(size_t)(BATCH + b) * MPAD * 32 + q2 * 32 + t2];
        float ssp = accs[(size_t)b * MPAD + q2];
        float ssg = accs[(size_t)(BATCH + b) * MPAD + q2];
        float lg = logits[(size_t)(b * NQ + q2) * NCLS + lab[t2]];
        float prob = __expf(lg - smx[q2]) / ssm[q2];
        float c = -prob + (ssp - dpm) * (1.0f / (float)HWP)
                + 1.0f - (2.0f * dsg + 1.0f) / (ssg + tcs[t2] + 1.0f);
        if (isnan(c)) c = (float)BIGV;
        else if (isinf(c)) c = (c > 0.f) ? (float)BIGV : -(float)BIGV;
        Ct[t2][q2] = (double)c;
    }
    __syncthreads();

    const int c0 = lane + 1;
    const bool valid1 = (lane < NQ - 64);
    const int c1 = lane + 65;
    const int cidx1 = valid1 ? (lane + 64) : 0;

    double v0 = 0.0, v1 = 0.0;
    int p0 = 0, p1 = 0;
    double u_reg = 0.0;                       // mirror of u[lane] (lanes 0..32)

    for (int i = 1; i <= NT; ++i) {
        double minv0 = 1e300, minv1 = 1e300;
        int way0 = 0, way1 = 0;
        bool used0 = false, used1 = !valid1;
        double du0 = 0.0, du1 = 0.0, dtot = 0.0;
        int j0 = 0, i0 = i;
        int jfin = 0;

        for (int guard = 0; guard < 160; ++guard) {
            double u_i0 = __shfl(u_reg, i0, 64);     // reg-mirror broadcast
            double cur0 = Ct[i0 - 1][lane] - u_i0 - v0;
            if (!used0 && cur0 < minv0) { minv0 = cur0; way0 = j0; }
            double cur1 = Ct[i0 - 1][cidx1] - u_i0 - v1;
            if (!used1 && cur1 < minv1) { minv1 = cur1; way1 = j0; }
            double bv = 1e301; int bj = 1 << 20;
            if (!used0) { bv = minv0; bj = c0; }
            if (!used1 && minv1 < bv) { bv = minv1; bj = c1; }
#pragma unroll
            for (int s = 32; s > 0; s >>= 1) {
                double ov = __shfl_down(bv, s, 64);
                int    oj = __shfl_down(bj, s, 64);
                if (ov < bv || (ov == bv && oj < bj)) { bv = ov; bj = oj; }
            }
            double delta = __shfl(bv, 0, 64);
            int j1 = __shfl(bj, 0, 64);
            dtot += delta;
            if (used0) { v0 -= delta; du0 += delta; } else { minv0 -= delta; }
            if (valid1) {
                if (used1) { v1 -= delta; du1 += delta; } else { minv1 -= delta; }
            }
            if (c0 == j1) used0 = true;
            if (valid1 && c1 == j1) used1 = true;
            int src = (j1 - 1) & 63, slot = (j1 - 1) >> 6;
            int pa = __shfl(p0, src, 64), pb = __shfl(p1, src, 64);
            int pj1 = slot ? pb : pa;
            if (pj1 == 0) { jfin = j1; break; }
            j0 = j1; i0 = pj1;
        }

        // deferred u updates (distinct rows across used cols -> race-free)
        if (used0 && p0 != 0) u[p0] += du0;
        if (valid1 && used1 && p1 != 0) u[p1] += du1;
        if (lane == 0) u[i] += dtot;

        int jj = jfin;
        for (int guard = 0; guard < 160 && jj != 0; ++guard) {
            int src = (jj - 1) & 63, slot = (jj - 1) >> 6;
            int wa = __shfl(way0, src, 64), wb = __shfl(way1, src, 64);
            int jprev = slot ? wb : wa;
            int pnew;
            if (jprev == 0) pnew = i;
            else {
                int s2 = (jprev - 1) & 63, sl2 = (jprev - 1) >> 6;
                int pa = __shfl(p0, s2, 64), pb = __shfl(p1, s2, 64);
                pnew = sl2 ? pb : pa;
            }
            if (c0 == jj) p0 = pnew;
            if (valid1 && c1 == jj) p1 = pnew;
            jj = jprev;
        }
        __syncthreads();
        u_reg = (lane <= NT) ? u[lane] : 0.0;   // refresh mirror once per row
    }

    unsigned long long m0 = __ballot(p0 != 0);
    unsigned long long m1 = __ballot(valid1 && p1 != 0);
    int base = b * NT;
    if (p0 != 0) {
        int rank = __popcll(m0 & ((1ull << lane) - 1ull));
        out[base + rank] = c0 - 1;
        out[BATCH * NT + base + rank] = p0 - 1;
    }
    if (valid1 && p1 != 0) {
        int rank = __popcll(m0) + __popcll(m1 & ((1ull << lane) - 1ull));
        out[base + rank] = c1 - 1;
        out[BATCH * NT + base + rank] = p1 - 1;
    }
}

// -------------------------------------------------------------------------
extern "C" void kernel_launch(void* const* d_in, const int* in_sizes, int n_in,
                              void* d_out, int out_size, void* d_ws, size_t ws_size,
                              hipStream_t stream) {
    const float* logits = (const float*)d_in[0];   // [8,100,81]
    const float* pmasks = (const float*)d_in[1];   // [8,100,256,256]
    const float* tmasks = (const float*)d_in[2];   // [8,32,512,512]
    const int*   labels = (const int*)d_in[3];     // [8,32]

    uint8_t* ws = (uint8_t*)d_ws;
    uint32_t* packed = (uint32_t*)ws;                       // 2 MiB
    uint8_t* zbase = ws + (size_t)BATCH * HWP * 4;
    float* accd = (float*)zbase;                            // 229376 B
    float* accs = (float*)(zbase + 229376);                 // 7168 B  (contiguous with accd)

    int* out = (int*)d_out;   // int32: src [8,32] then tgt [8,32]

    pack_kernel<<<BATCH * HWP / 512, 256, 0, stream>>>(tmasks, packed, accd);
    mfma_kernel<<<dim3(KSPLIT, MTILES, BATCH), 256, 0, stream>>>(pmasks, packed, accd, accs);
    hungarian_kernel<<<BATCH, 64, 0, stream>>>(logits, labels, accd, accs, out);
}

// Round 3
// 586.085 us; speedup vs baseline: 1.0080x; 1.0080x over previous
//
#include <hip/hip_runtime.h>
#include <stdint.h>

// HungarianMatcher on MI355X — round 7: Hungarian critical-path cut.
// Round 6 null result proved pack/mfma are at their HBM floors (134/210 MB);
// the only controllable slack left is the single-wave JV solver's serial
// chain. This round removes the per-row sync/LDS round trips:
//   * u[] lives in registers (lane L owns u[L]); deferred row-end updates
//     are scattered via ds_permute (distinct target rows -> collision-free;
//     unwritten lanes read 0; lane 63 is the trash sink). No per-row
//     __syncthreads (each one forced a full waitcnt drain) and no LDS
//     refresh read on the chain.
//   * Ct padded to [32][128] doubles: slot-1 column = lane+64 for ALL lanes
//     (dummy cols = 1e30, never win the min) -> valid1 selects vanish and
//     the two Ct reads share one base (ds_read2_b64-able).
// pack/mfma kernels unchanged from round 6.

#define BATCH 8
#define NQ    100
#define NT    32
#define HWP   65536      // 256*256
#define NCLS  81
#define BIGV  1.0e6
#define MPAD  112        // 7*16
#define MTILES 7
#define KSPLIT 16
#define KC (HWP / KSPLIT)   // 4096 px per block
#define KW (KC / 4)         // 1024 px per wave
#define NITER (KW / 64)     // 16 k-iters of 64 px
#define NZFLOAT 59136       // (2*BATCH*MPAD*32 + 2*BATCH*MPAD) floats

typedef __attribute__((ext_vector_type(8))) short short8;
typedef __attribute__((ext_vector_type(4))) float f32x4;

union FragU { short8 s; uint32_t w[4]; };

__device__ inline uint32_t cvt_pk_bf16(float lo, float hi) {  // RNE packed cvt
    uint32_t r;
    asm("v_cvt_pk_bf16_f32 %0, %1, %2" : "=v"(r) : "v"(lo), "v"(hi));
    return r;
}

// expand bit r (lo halves) / bit r+16 (hi halves) of two packed words into
// two bf16-pair words: value 1.0 (0x3F80) or 0 per half.
__device__ inline void bpair(uint32_t wlo, uint32_t whi, int r,
                             uint32_t& lofrag, uint32_t& hifrag) {
    uint32_t a = wlo >> r;
    uint32_t c = whi >> r;
    uint32_t mlo = (a & 1u) | ((c & 1u) << 16);
    uint32_t mhi = ((a >> 16) & 1u) | (((c >> 16) & 1u) << 16);
    lofrag = (mlo << 14) - (mlo << 7);
    hifrag = (mhi << 14) - (mhi << 7);
}

// push double v to lane tgt across the wave; lanes nobody targets receive 0.
__device__ inline double perm_scatter_d(int tgt, double v) {
    int addr = tgt << 2;
    int lo = __builtin_amdgcn_ds_permute(addr, __double2loint(v));
    int hi = __builtin_amdgcn_ds_permute(addr, __double2hiint(v));
    return __hiloint2double(hi, lo);
}

// -------------------------------------------------------------------------
// Pure threshold-copy: 2 output px per thread via one float4 (contiguous
// 16 B/lane), uint2 packed store. Also zeros accd/accs (replaces memset).
__global__ __launch_bounds__(256) void pack_kernel(const float* __restrict__ tmask,
                                                   uint32_t* __restrict__ packed,
                                                   float* __restrict__ zbuf) {
    int idx = blockIdx.x * 256 + threadIdx.x;   // BATCH * HWP/2 threads
    if (idx < NZFLOAT) zbuf[idx] = 0.f;         // fused accumulator clear
    int b  = idx >> 15;                         // 32768 pairs per batch
    int pp = idx & 32767;
    int y  = pp >> 7;                           // out row (in row = 2y)
    int xp = pp & 127;                          // pair: out x = 2xp, 2xp+1
    const float* base = tmask + (size_t)b * NT * 262144 + (size_t)(2 * y) * 512 + 4 * xp;
    uint32_t w0 = 0, w1 = 0;
#pragma unroll
    for (int t = 0; t < NT; ++t) {
        float4 v = *(const float4*)(base + (size_t)t * 262144);
        w0 |= (v.x > 0.5f ? 1u : 0u) << t;
        w1 |= (v.z > 0.5f ? 1u : 0u) << t;
    }
    int p0 = y * 256 + 2 * xp;
    *(uint2*)(packed + (size_t)b * HWP + p0) = make_uint2(w0, w1);
}

// -------------------------------------------------------------------------
// accd: [2][BATCH][MPAD][32] fp32 (dot_pm, dot_sig); accs: [2][BATCH][MPAD]
// Row 100 of the dot_pm accumulator carries the target-mask pixel counts
// (A-row 100 forced to bf16 ones; integer sums < 2^24 -> exact in f32).
__global__ __launch_bounds__(256) void mfma_kernel(const float* __restrict__ pmask,
                                                   const uint32_t* __restrict__ packed,
                                                   float* __restrict__ accd,
                                                   float* __restrict__ accs) {
    const int kblk = blockIdx.x;
    const int mt   = blockIdx.y;
    const int b    = blockIdx.z;
    const int tid  = threadIdx.x;
    const int wv   = tid >> 6, lane = tid & 63;
    const int m0   = mt * 16;
    const int q    = lane >> 4;    // 0..3  (k-quad)
    const int r    = lane & 15;    // 0..15 (A row / B target)

    __shared__ float Cred[8][16][32];

    const bool onesrow = (m0 + r == 100);                  // counts row
    int mrow = m0 + r; if (mrow > NQ - 1) mrow = NQ - 1;   // pad rows dup row 99
    const float* Arow = pmask + (size_t)b * NQ * HWP + (size_t)mrow * HWP;
    const uint32_t* pkb = packed + (size_t)b * HWP;
    const int kbase0 = kblk * KC + wv * KW;

    f32x4 Cpm0 = {0,0,0,0}, Cpm1 = {0,0,0,0}, Csg0 = {0,0,0,0}, Csg1 = {0,0,0,0};
    float rsp = 0.f, rsg = 0.f;

    for (int ki = 0; ki < NITER; ++ki) {
        const int kb = kbase0 + ki * 64;
        // --- direct fragment loads (no LDS) ---
        const float4 va0 = *(const float4*)(Arow + kb + q * 8);
        const float4 va1 = *(const float4*)(Arow + kb + q * 8 + 4);
        const float4 va2 = *(const float4*)(Arow + kb + 32 + q * 8);
        const float4 va3 = *(const float4*)(Arow + kb + 32 + q * 8 + 4);
        const uint4  wb0 = *(const uint4*)(pkb + kb + q * 8);
        const uint4  wb1 = *(const uint4*)(pkb + kb + q * 8 + 4);
        const uint4  wb2 = *(const uint4*)(pkb + kb + 32 + q * 8);
        const uint4  wb3 = *(const uint4*)(pkb + kb + 32 + q * 8 + 4);

        FragU a0, a1, g0, g1;
        auto proc4 = [&](const float4& v, uint32_t* aw, uint32_t* gw) {
            float sg[4];
#pragma unroll
            for (int e = 0; e < 4; ++e) {
                float pv = (&v.x)[e];
                float ax = fabsf(pv);
                float en = __expf(-ax);
                float one_en = 1.0f + en;
                float inv = __builtin_amdgcn_rcpf(one_en);
                float sig = (pv >= 0.f) ? inv : en * inv;
                float sp  = fmaxf(pv, 0.f) + __logf(one_en);
                rsp += sp; rsg += sig;
                sg[e] = sig;
            }
            aw[0] = cvt_pk_bf16(v.x, v.y);
            aw[1] = cvt_pk_bf16(v.z, v.w);
            gw[0] = cvt_pk_bf16(sg[0], sg[1]);
            gw[1] = cvt_pk_bf16(sg[2], sg[3]);
        };
        proc4(va0, &a0.w[0], &g0.w[0]);
        proc4(va1, &a0.w[2], &g0.w[2]);
        proc4(va2, &a1.w[0], &g1.w[0]);
        proc4(va3, &a1.w[2], &g1.w[2]);

        if (onesrow) {   // A-row 100 = bf16 ones -> counts
#pragma unroll
            for (int i2 = 0; i2 < 4; ++i2) { a0.w[i2] = 0x3F803F80u; a1.w[i2] = 0x3F803F80u; }
        }

        FragU b00, b01, b10, b11;
        bpair(wb0.x, wb0.y, r, b00.w[0], b10.w[0]);
        bpair(wb0.z, wb0.w, r, b00.w[1], b10.w[1]);
        bpair(wb1.x, wb1.y, r, b00.w[2], b10.w[2]);
        bpair(wb1.z, wb1.w, r, b00.w[3], b10.w[3]);
        bpair(wb2.x, wb2.y, r, b01.w[0], b11.w[0]);
        bpair(wb2.z, wb2.w, r, b01.w[1], b11.w[1]);
        bpair(wb3.x, wb3.y, r, b01.w[2], b11.w[2]);
        bpair(wb3.z, wb3.w, r, b01.w[3], b11.w[3]);

        Cpm0 = __builtin_amdgcn_mfma_f32_16x16x32_bf16(a0.s, b00.s, Cpm0, 0, 0, 0);
        Cpm0 = __builtin_amdgcn_mfma_f32_16x16x32_bf16(a1.s, b01.s, Cpm0, 0, 0, 0);
        Cpm1 = __builtin_amdgcn_mfma_f32_16x16x32_bf16(a0.s, b10.s, Cpm1, 0, 0, 0);
        Cpm1 = __builtin_amdgcn_mfma_f32_16x16x32_bf16(a1.s, b11.s, Cpm1, 0, 0, 0);
        Csg0 = __builtin_amdgcn_mfma_f32_16x16x32_bf16(g0.s, b00.s, Csg0, 0, 0, 0);
        Csg0 = __builtin_amdgcn_mfma_f32_16x16x32_bf16(g1.s, b01.s, Csg0, 0, 0, 0);
        Csg1 = __builtin_amdgcn_mfma_f32_16x16x32_bf16(g0.s, b10.s, Csg1, 0, 0, 0);
        Csg1 = __builtin_amdgcn_mfma_f32_16x16x32_bf16(g1.s, b11.s, Csg1, 0, 0, 0);
    }

    // row sums: reduce across the 4 k-quads (lane bits 4,5) -> q==0 lanes
    rsp += __shfl_xor(rsp, 16, 64);
    rsp += __shfl_xor(rsp, 32, 64);
    rsg += __shfl_xor(rsg, 16, 64);
    rsg += __shfl_xor(rsg, 32, 64);
    if (q == 0 && m0 + r < NQ) {
        atomicAdd(&accs[(size_t)b * MPAD + m0 + r], rsp);
        atomicAdd(&accs[(size_t)(BATCH + b) * MPAD + m0 + r], rsg);
    }

    // C/D layout: col = lane&15 (target), row = (lane>>4)*4 + e (query)
#pragma unroll
    for (int e = 0; e < 4; ++e) {
        const int m = q * 4 + e;
        Cred[wv * 2 + 0][m][r]      = Cpm0[e];
        Cred[wv * 2 + 0][m][16 + r] = Cpm1[e];
        Cred[wv * 2 + 1][m][r]      = Csg0[e];
        Cred[wv * 2 + 1][m][16 + r] = Csg1[e];
    }
    __syncthreads();
    for (int idx = tid; idx < 1024; idx += 256) {
        const int type = idx >> 9, rem = idx & 511, m = rem >> 5, n = rem & 31;
        float s = Cred[0 + type][m][n] + Cred[2 + type][m][n]
                + Cred[4 + type][m][n] + Cred[6 + type][m][n];
        const int gm = m0 + m;
        if (gm < 101)   // rows 0..99 = queries, row 100 = tm counts
            atomicAdd(&accd[(size_t)(type * BATCH + b) * MPAD * 32 + (size_t)gm * 32 + n], s);
    }
}

// -------------------------------------------------------------------------
// Finalize cost matrix + exact single-wave JV Hungarian.
// Single wave: register-resident u[] (lane L owns u[L]), ds_permute scatter
// for deferred row-end updates, no barriers on the augment chain.
__global__ __launch_bounds__(64) void hungarian_kernel(const float* __restrict__ logits,
                                                       const int* __restrict__ labels,
                                                       const float* __restrict__ accd,
                                                       const float* __restrict__ accs,
                                                       int* __restrict__ out) {
    const int b = blockIdx.x;
    const int lane = threadIdx.x;

    __shared__ double Ct[NT][128];          // cols 100..127 = dummy (1e30)
    __shared__ float smx[NQ], ssm[NQ];
    __shared__ float tcs[NT];
    __shared__ int lab[NT];

    if (lane < NT) {
        tcs[lane] = accd[(size_t)b * MPAD * 32 + 100 * 32 + lane];  // MFMA-computed counts
        lab[lane] = labels[b * NT + lane];
    }
    for (int n = lane; n < NQ; n += 64) {
        const float* lg = logits + (size_t)(b * NQ + n) * NCLS;
        float mx = -1e30f;
        for (int c = 0; c < NCLS; ++c) mx = fmaxf(mx, lg[c]);
        float s = 0.f;
        for (int c = 0; c < NCLS; ++c) s += __expf(lg[c] - mx);
        smx[n] = mx; ssm[n] = s;
    }
    __syncthreads();
    for (int idx = lane; idx < NT * 128; idx += 64) {
        const int t2 = idx >> 7, q2 = idx & 127;
        if (q2 < NQ) {
            float dpm = accd[(size_t)b * MPAD * 32 + q2 * 32 + t2];
            float dsg = accd[(size_t)(BATCH + b) * MPAD * 32 + q2 * 32 + t2];
            float ssp = accs[(size_t)b * MPAD + q2];
            float ssg = accs[(size_t)(BATCH + b) * MPAD + q2];
            float lg = logits[(size_t)(b * NQ + q2) * NCLS + lab[t2]];
            float prob = __expf(lg - smx[q2]) / ssm[q2];
            float c = -prob + (ssp - dpm) * (1.0f / (float)HWP)
                    + 1.0f - (2.0f * dsg + 1.0f) / (ssg + tcs[t2] + 1.0f);
            if (isnan(c)) c = (float)BIGV;
            else if (isinf(c)) c = (c > 0.f) ? (float)BIGV : -(float)BIGV;
            Ct[t2][q2] = (double)c;
        } else {
            Ct[t2][q2] = 1.0e30;            // dummy col: never wins the min
        }
    }
    __syncthreads();

    const int c0 = lane + 1;                // JV col ids (1-based)
    const int c1 = lane + 65;               // 65..128 (101..128 are dummies)

    double v0 = 0.0, v1 = 0.0;
    int p0 = 0, p1 = 0;
    double u_reg = 0.0;                     // lane L owns u[L]; lane 63 = trash sink

    for (int i = 1; i <= NT; ++i) {
        double minv0 = 1e300, minv1 = 1e300;
        int way0 = 0, way1 = 0;
        bool used0 = false, used1 = false;
        double du0 = 0.0, du1 = 0.0, dtot = 0.0;
        int j0 = 0, i0 = i;
        int jfin = 0;

        for (int guard = 0; guard < 160; ++guard) {
            double u_i0 = __shfl(u_reg, i0, 64);     // register-u broadcast
            const double* ctrow = &Ct[i0 - 1][0];    // shared base -> ds_read2-able
            double cur0 = ctrow[lane]      - u_i0 - v0;
            double cur1 = ctrow[lane + 64] - u_i0 - v1;
            if (!used0 && cur0 < minv0) { minv0 = cur0; way0 = j0; }
            if (!used1 && cur1 < minv1) { minv1 = cur1; way1 = j0; }
            double bv = 1e301; int bj = 1 << 20;
            if (!used0) { bv = minv0; bj = c0; }
            if (!used1 && minv1 < bv) { bv = minv1; bj = c1; }
#pragma unroll
            for (int s = 32; s > 0; s >>= 1) {
                double ov = __shfl_down(bv, s, 64);
                int    oj = __shfl_down(bj, s, 64);
                if (ov < bv || (ov == bv && oj < bj)) { bv = ov; bj = oj; }
            }
            double delta = __shfl(bv, 0, 64);
            int j1 = __shfl(bj, 0, 64);
            dtot += delta;
            if (used0) { v0 -= delta; du0 += delta; } else { minv0 -= delta; }
            if (used1) { v1 -= delta; du1 += delta; } else { minv1 -= delta; }
            if (c0 == j1) used0 = true;
            if (c1 == j1) used1 = true;
            int src = (j1 - 1) & 63, slot = (j1 - 1) >> 6;
            int pa = __shfl(p0, src, 64), pb = __shfl(p1, src, 64);
            int pj1 = slot ? pb : pa;
            if (pj1 == 0) { jfin = j1; break; }
            j0 = j1; i0 = pj1;
        }

        // deferred u updates: scatter du to owning lanes (distinct rows across
        // used cols -> collision-free; lane 63 takes the discards).
        int t0 = (used0 && p0 != 0) ? p0 : 63;
        int t1 = (used1 && p1 != 0) ? p1 : 63;
        u_reg += perm_scatter_d(t0, du0) + perm_scatter_d(t1, du1);
        if (lane == i) u_reg += dtot;       // dtot is wave-uniform

        int jj = jfin;
        for (int guard = 0; guard < 160 && jj != 0; ++guard) {
            int src = (jj - 1) & 63, slot = (jj - 1) >> 6;
            int wa = __shfl(way0, src, 64), wb = __shfl(way1, src, 64);
            int jprev = slot ? wb : wa;
            int pnew;
            if (jprev == 0) pnew = i;
            else {
                int s2 = (jprev - 1) & 63, sl2 = (jprev - 1) >> 6;
                int pa = __shfl(p0, s2, 64), pb = __shfl(p1, s2, 64);
                pnew = sl2 ? pb : pa;
            }
            if (c0 == jj) p0 = pnew;
            if (c1 == jj) p1 = pnew;
            jj = jprev;
        }
    }

    unsigned long long m0 = __ballot(p0 != 0);
    unsigned long long m1 = __ballot(p1 != 0);
    int base = b * NT;
    if (p0 != 0) {
        int rank = __popcll(m0 & ((1ull << lane) - 1ull));
        out[base + rank] = c0 - 1;
        out[BATCH * NT + base + rank] = p0 - 1;
    }
    if (p1 != 0) {
        int rank = __popcll(m0) + __popcll(m1 & ((1ull << lane) - 1ull));
        out[base + rank] = c1 - 1;
        out[BATCH * NT + base + rank] = p1 - 1;
    }
}

// -------------------------------------------------------------------------
extern "C" void kernel_launch(void* const* d_in, const int* in_sizes, int n_in,
                              void* d_out, int out_size, void* d_ws, size_t ws_size,
                              hipStream_t stream) {
    const float* logits = (const float*)d_in[0];   // [8,100,81]
    const float* pmasks = (const float*)d_in[1];   // [8,100,256,256]
    const float* tmasks = (const float*)d_in[2];   // [8,32,512,512]
    const int*   labels = (const int*)d_in[3];     // [8,32]

    uint8_t* ws = (uint8_t*)d_ws;
    uint32_t* packed = (uint32_t*)ws;                       // 2 MiB
    uint8_t* zbase = ws + (size_t)BATCH * HWP * 4;
    float* accd = (float*)zbase;                            // 229376 B
    float* accs = (float*)(zbase + 229376);                 // 7168 B  (contiguous with accd)

    int* out = (int*)d_out;   // int32: src [8,32] then tgt [8,32]

    pack_kernel<<<BATCH * HWP / 512, 256, 0, stream>>>(tmasks, packed, accd);
    mfma_kernel<<<dim3(KSPLIT, MTILES, BATCH), 256, 0, stream>>>(pmasks, packed, accd, accs);
    hungarian_kernel<<<BATCH, 64, 0, stream>>>(logits, labels, accd, accs, out);
}

// Round 4
// 575.354 us; speedup vs baseline: 1.0268x; 1.0187x over previous
//
#include <hip/hip_runtime.h>
#include <stdint.h>

// HungarianMatcher on MI355X — round 8: Hungarian uniform-gather + ballot argmin.
// r7 confirmed the augment chain is the last controllable slack. This round
// attacks per-iteration latency (~550 cyc -> ~350):
//   * every cross-lane gather with a WAVE-UNIFORM source lane (u[i0], p[src],
//     way[src] in both loops) becomes v_readlane (~8 cyc SGPR broadcast)
//     instead of ds_bpermute-based __shfl (~40 cyc).
//   * argmin: value-only f64 min butterfly (no index payload / cndmask chain),
//     then equality ballot + ffs recovers the col. Tie-break identical to the
//     old (ov==bv && oj<bj): slot0 cols (1..64) always < slot1 cols (65..128),
//     and ffs = smallest lane = smallest col. delta is a bit-exact copy of a
//     lane's minv, so == is exact.
// pack/mfma unchanged (at their 134/210 MB HBM floors, r6 null result).

#define BATCH 8
#define NQ    100
#define NT    32
#define HWP   65536      // 256*256
#define NCLS  81
#define BIGV  1.0e6
#define MPAD  112        // 7*16
#define MTILES 7
#define KSPLIT 16
#define KC (HWP / KSPLIT)   // 4096 px per block
#define KW (KC / 4)         // 1024 px per wave
#define NITER (KW / 64)     // 16 k-iters of 64 px
#define NZFLOAT 59136       // (2*BATCH*MPAD*32 + 2*BATCH*MPAD) floats

typedef __attribute__((ext_vector_type(8))) short short8;
typedef __attribute__((ext_vector_type(4))) float f32x4;

union FragU { short8 s; uint32_t w[4]; };

__device__ inline uint32_t cvt_pk_bf16(float lo, float hi) {  // RNE packed cvt
    uint32_t r;
    asm("v_cvt_pk_bf16_f32 %0, %1, %2" : "=v"(r) : "v"(lo), "v"(hi));
    return r;
}

// expand bit r (lo halves) / bit r+16 (hi halves) of two packed words into
// two bf16-pair words: value 1.0 (0x3F80) or 0 per half.
__device__ inline void bpair(uint32_t wlo, uint32_t whi, int r,
                             uint32_t& lofrag, uint32_t& hifrag) {
    uint32_t a = wlo >> r;
    uint32_t c = whi >> r;
    uint32_t mlo = (a & 1u) | ((c & 1u) << 16);
    uint32_t mhi = ((a >> 16) & 1u) | (((c >> 16) & 1u) << 16);
    lofrag = (mlo << 14) - (mlo << 7);
    hifrag = (mhi << 14) - (mhi << 7);
}

// push double v to lane tgt across the wave; lanes nobody targets receive 0.
__device__ inline double perm_scatter_d(int tgt, double v) {
    int addr = tgt << 2;
    int lo = __builtin_amdgcn_ds_permute(addr, __double2loint(v));
    int hi = __builtin_amdgcn_ds_permute(addr, __double2hiint(v));
    return __hiloint2double(hi, lo);
}

// uniform-lane gather of a double: 2x v_readlane (SGPR broadcast), ~8 cyc
// vs ~40 for ds_bpermute-based __shfl. 'lane' MUST be wave-uniform.
__device__ inline double readlane_d(double v, int lane) {
    int lo = __builtin_amdgcn_readlane(__double2loint(v), lane);
    int hi = __builtin_amdgcn_readlane(__double2hiint(v), lane);
    return __hiloint2double(hi, lo);
}

// -------------------------------------------------------------------------
// Pure threshold-copy: 2 output px per thread via one float4 (contiguous
// 16 B/lane), uint2 packed store. Also zeros accd/accs (replaces memset).
__global__ __launch_bounds__(256) void pack_kernel(const float* __restrict__ tmask,
                                                   uint32_t* __restrict__ packed,
                                                   float* __restrict__ zbuf) {
    int idx = blockIdx.x * 256 + threadIdx.x;   // BATCH * HWP/2 threads
    if (idx < NZFLOAT) zbuf[idx] = 0.f;         // fused accumulator clear
    int b  = idx >> 15;                         // 32768 pairs per batch
    int pp = idx & 32767;
    int y  = pp >> 7;                           // out row (in row = 2y)
    int xp = pp & 127;                          // pair: out x = 2xp, 2xp+1
    const float* base = tmask + (size_t)b * NT * 262144 + (size_t)(2 * y) * 512 + 4 * xp;
    uint32_t w0 = 0, w1 = 0;
#pragma unroll
    for (int t = 0; t < NT; ++t) {
        float4 v = *(const float4*)(base + (size_t)t * 262144);
        w0 |= (v.x > 0.5f ? 1u : 0u) << t;
        w1 |= (v.z > 0.5f ? 1u : 0u) << t;
    }
    int p0 = y * 256 + 2 * xp;
    *(uint2*)(packed + (size_t)b * HWP + p0) = make_uint2(w0, w1);
}

// -------------------------------------------------------------------------
// accd: [2][BATCH][MPAD][32] fp32 (dot_pm, dot_sig); accs: [2][BATCH][MPAD]
// Row 100 of the dot_pm accumulator carries the target-mask pixel counts
// (A-row 100 forced to bf16 ones; integer sums < 2^24 -> exact in f32).
__global__ __launch_bounds__(256) void mfma_kernel(const float* __restrict__ pmask,
                                                   const uint32_t* __restrict__ packed,
                                                   float* __restrict__ accd,
                                                   float* __restrict__ accs) {
    const int kblk = blockIdx.x;
    const int mt   = blockIdx.y;
    const int b    = blockIdx.z;
    const int tid  = threadIdx.x;
    const int wv   = tid >> 6, lane = tid & 63;
    const int m0   = mt * 16;
    const int q    = lane >> 4;    // 0..3  (k-quad)
    const int r    = lane & 15;    // 0..15 (A row / B target)

    __shared__ float Cred[8][16][32];

    const bool onesrow = (m0 + r == 100);                  // counts row
    int mrow = m0 + r; if (mrow > NQ - 1) mrow = NQ - 1;   // pad rows dup row 99
    const float* Arow = pmask + (size_t)b * NQ * HWP + (size_t)mrow * HWP;
    const uint32_t* pkb = packed + (size_t)b * HWP;
    const int kbase0 = kblk * KC + wv * KW;

    f32x4 Cpm0 = {0,0,0,0}, Cpm1 = {0,0,0,0}, Csg0 = {0,0,0,0}, Csg1 = {0,0,0,0};
    float rsp = 0.f, rsg = 0.f;

    for (int ki = 0; ki < NITER; ++ki) {
        const int kb = kbase0 + ki * 64;
        // --- direct fragment loads (no LDS) ---
        const float4 va0 = *(const float4*)(Arow + kb + q * 8);
        const float4 va1 = *(const float4*)(Arow + kb + q * 8 + 4);
        const float4 va2 = *(const float4*)(Arow + kb + 32 + q * 8);
        const float4 va3 = *(const float4*)(Arow + kb + 32 + q * 8 + 4);
        const uint4  wb0 = *(const uint4*)(pkb + kb + q * 8);
        const uint4  wb1 = *(const uint4*)(pkb + kb + q * 8 + 4);
        const uint4  wb2 = *(const uint4*)(pkb + kb + 32 + q * 8);
        const uint4  wb3 = *(const uint4*)(pkb + kb + 32 + q * 8 + 4);

        FragU a0, a1, g0, g1;
        auto proc4 = [&](const float4& v, uint32_t* aw, uint32_t* gw) {
            float sg[4];
#pragma unroll
            for (int e = 0; e < 4; ++e) {
                float pv = (&v.x)[e];
                float ax = fabsf(pv);
                float en = __expf(-ax);
                float one_en = 1.0f + en;
                float inv = __builtin_amdgcn_rcpf(one_en);
                float sig = (pv >= 0.f) ? inv : en * inv;
                float sp  = fmaxf(pv, 0.f) + __logf(one_en);
                rsp += sp; rsg += sig;
                sg[e] = sig;
            }
            aw[0] = cvt_pk_bf16(v.x, v.y);
            aw[1] = cvt_pk_bf16(v.z, v.w);
            gw[0] = cvt_pk_bf16(sg[0], sg[1]);
            gw[1] = cvt_pk_bf16(sg[2], sg[3]);
        };
        proc4(va0, &a0.w[0], &g0.w[0]);
        proc4(va1, &a0.w[2], &g0.w[2]);
        proc4(va2, &a1.w[0], &g1.w[0]);
        proc4(va3, &a1.w[2], &g1.w[2]);

        if (onesrow) {   // A-row 100 = bf16 ones -> counts
#pragma unroll
            for (int i2 = 0; i2 < 4; ++i2) { a0.w[i2] = 0x3F803F80u; a1.w[i2] = 0x3F803F80u; }
        }

        FragU b00, b01, b10, b11;
        bpair(wb0.x, wb0.y, r, b00.w[0], b10.w[0]);
        bpair(wb0.z, wb0.w, r, b00.w[1], b10.w[1]);
        bpair(wb1.x, wb1.y, r, b00.w[2], b10.w[2]);
        bpair(wb1.z, wb1.w, r, b00.w[3], b10.w[3]);
        bpair(wb2.x, wb2.y, r, b01.w[0], b11.w[0]);
        bpair(wb2.z, wb2.w, r, b01.w[1], b11.w[1]);
        bpair(wb3.x, wb3.y, r, b01.w[2], b11.w[2]);
        bpair(wb3.z, wb3.w, r, b01.w[3], b11.w[3]);

        Cpm0 = __builtin_amdgcn_mfma_f32_16x16x32_bf16(a0.s, b00.s, Cpm0, 0, 0, 0);
        Cpm0 = __builtin_amdgcn_mfma_f32_16x16x32_bf16(a1.s, b01.s, Cpm0, 0, 0, 0);
        Cpm1 = __builtin_amdgcn_mfma_f32_16x16x32_bf16(a0.s, b10.s, Cpm1, 0, 0, 0);
        Cpm1 = __builtin_amdgcn_mfma_f32_16x16x32_bf16(a1.s, b11.s, Cpm1, 0, 0, 0);
        Csg0 = __builtin_amdgcn_mfma_f32_16x16x32_bf16(g0.s, b00.s, Csg0, 0, 0, 0);
        Csg0 = __builtin_amdgcn_mfma_f32_16x16x32_bf16(g1.s, b01.s, Csg0, 0, 0, 0);
        Csg1 = __builtin_amdgcn_mfma_f32_16x16x32_bf16(g0.s, b10.s, Csg1, 0, 0, 0);
        Csg1 = __builtin_amdgcn_mfma_f32_16x16x32_bf16(g1.s, b11.s, Csg1, 0, 0, 0);
    }

    // row sums: reduce across the 4 k-quads (lane bits 4,5) -> q==0 lanes
    rsp += __shfl_xor(rsp, 16, 64);
    rsp += __shfl_xor(rsp, 32, 64);
    rsg += __shfl_xor(rsg, 16, 64);
    rsg += __shfl_xor(rsg, 32, 64);
    if (q == 0 && m0 + r < NQ) {
        atomicAdd(&accs[(size_t)b * MPAD + m0 + r], rsp);
        atomicAdd(&accs[(size_t)(BATCH + b) * MPAD + m0 + r], rsg);
    }

    // C/D layout: col = lane&15 (target), row = (lane>>4)*4 + e (query)
#pragma unroll
    for (int e = 0; e < 4; ++e) {
        const int m = q * 4 + e;
        Cred[wv * 2 + 0][m][r]      = Cpm0[e];
        Cred[wv * 2 + 0][m][16 + r] = Cpm1[e];
        Cred[wv * 2 + 1][m][r]      = Csg0[e];
        Cred[wv * 2 + 1][m][16 + r] = Csg1[e];
    }
    __syncthreads();
    for (int idx = tid; idx < 1024; idx += 256) {
        const int type = idx >> 9, rem = idx & 511, m = rem >> 5, n = rem & 31;
        float s = Cred[0 + type][m][n] + Cred[2 + type][m][n]
                + Cred[4 + type][m][n] + Cred[6 + type][m][n];
        const int gm = m0 + m;
        if (gm < 101)   // rows 0..99 = queries, row 100 = tm counts
            atomicAdd(&accd[(size_t)(type * BATCH + b) * MPAD * 32 + (size_t)gm * 32 + n], s);
    }
}

// -------------------------------------------------------------------------
// Finalize cost matrix + exact single-wave JV Hungarian.
// Register-resident u[], readlane uniform gathers, ballot-based argmin.
__global__ __launch_bounds__(64) void hungarian_kernel(const float* __restrict__ logits,
                                                       const int* __restrict__ labels,
                                                       const float* __restrict__ accd,
                                                       const float* __restrict__ accs,
                                                       int* __restrict__ out) {
    const int b = blockIdx.x;
    const int lane = threadIdx.x;

    __shared__ double Ct[NT][128];          // cols 100..127 = dummy (1e30)
    __shared__ float smx[NQ], ssm[NQ];
    __shared__ float tcs[NT];
    __shared__ int lab[NT];

    if (lane < NT) {
        tcs[lane] = accd[(size_t)b * MPAD * 32 + 100 * 32 + lane];  // MFMA-computed counts
        lab[lane] = labels[b * NT + lane];
    }
    for (int n = lane; n < NQ; n += 64) {
        const float* lg = logits + (size_t)(b * NQ + n) * NCLS;
        float mx = -1e30f;
        for (int c = 0; c < NCLS; ++c) mx = fmaxf(mx, lg[c]);
        float s = 0.f;
        for (int c = 0; c < NCLS; ++c) s += __expf(lg[c] - mx);
        smx[n] = mx; ssm[n] = s;
    }
    __syncthreads();
    for (int idx = lane; idx < NT * 128; idx += 64) {
        const int t2 = idx >> 7, q2 = idx & 127;
        if (q2 < NQ) {
            float dpm = accd[(size_t)b * MPAD * 32 + q2 * 32 + t2];
            float dsg = accd[(size_t)(BATCH + b) * MPAD * 32 + q2 * 32 + t2];
            float ssp = accs[(size_t)b * MPAD + q2];
            float ssg = accs[(size_t)(BATCH + b) * MPAD + q2];
            float lg = logits[(size_t)(b * NQ + q2) * NCLS + lab[t2]];
            float prob = __expf(lg - smx[q2]) / ssm[q2];
            float c = -prob + (ssp - dpm) * (1.0f / (float)HWP)
                    + 1.0f - (2.0f * dsg + 1.0f) / (ssg + tcs[t2] + 1.0f);
            if (isnan(c)) c = (float)BIGV;
            else if (isinf(c)) c = (c > 0.f) ? (float)BIGV : -(float)BIGV;
            Ct[t2][q2] = (double)c;
        } else {
            Ct[t2][q2] = 1.0e30;            // dummy col: never wins the min
        }
    }
    __syncthreads();

    const int c0 = lane + 1;                // JV col ids (1-based)
    const int c1 = lane + 65;               // 65..128 (101..128 are dummies)

    double v0 = 0.0, v1 = 0.0;
    int p0 = 0, p1 = 0;
    double u_reg = 0.0;                     // lane L owns u[L]; lane 63 = trash sink

    for (int i = 1; i <= NT; ++i) {
        double minv0 = 1e300, minv1 = 1e300;
        int way0 = 0, way1 = 0;
        bool used0 = false, used1 = false;
        double du0 = 0.0, du1 = 0.0, dtot = 0.0;
        int j0 = 0, i0 = i;
        int jfin = 0;

        for (int guard = 0; guard < 160; ++guard) {
            double u_i0 = readlane_d(u_reg, i0);     // uniform gather (~8cyc)
            const double* ctrow = &Ct[i0 - 1][0];
            double cur0 = ctrow[lane]      - u_i0 - v0;
            double cur1 = ctrow[lane + 64] - u_i0 - v1;
            if (!used0 && cur0 < minv0) { minv0 = cur0; way0 = j0; }
            if (!used1 && cur1 < minv1) { minv1 = cur1; way1 = j0; }
            // value-only min butterfly (no index payload)
            double bv = used0 ? 1e301 : minv0;
            if (!used1 && minv1 < bv) bv = minv1;
#pragma unroll
            for (int s = 32; s > 0; s >>= 1) {
                double ov = __shfl_down(bv, s, 64);
                if (ov < bv) bv = ov;
            }
            double delta = readlane_d(bv, 0);
            // argmin via equality ballot: smallest col first (slot0 < slot1,
            // ffs = smallest lane). delta is bit-exact copy of a minv -> == safe.
            unsigned long long e0 = __ballot(!used0 && minv0 == delta);
            unsigned long long e1 = __ballot(!used1 && minv1 == delta);
            int j1 = e0 ? __ffsll((unsigned long long)e0)
                        : (64 + __ffsll((unsigned long long)e1));
            dtot += delta;
            if (used0) { v0 -= delta; du0 += delta; } else { minv0 -= delta; }
            if (used1) { v1 -= delta; du1 += delta; } else { minv1 -= delta; }
            if (c0 == j1) used0 = true;
            if (c1 == j1) used1 = true;
            int src = (j1 - 1) & 63, slot = (j1 - 1) >> 6;
            int pa = __builtin_amdgcn_readlane(p0, src);
            int pb = __builtin_amdgcn_readlane(p1, src);
            int pj1 = slot ? pb : pa;
            if (pj1 == 0) { jfin = j1; break; }
            j0 = j1; i0 = pj1;
        }

        // deferred u updates: scatter du to owning lanes (distinct rows across
        // used cols -> collision-free; lane 63 takes the discards).
        int t0 = (used0 && p0 != 0) ? p0 : 63;
        int t1 = (used1 && p1 != 0) ? p1 : 63;
        u_reg += perm_scatter_d(t0, du0) + perm_scatter_d(t1, du1);
        if (lane == i) u_reg += dtot;       // dtot is wave-uniform

        int jj = jfin;
        for (int guard = 0; guard < 160 && jj != 0; ++guard) {
            int src = (jj - 1) & 63, slot = (jj - 1) >> 6;
            int wa = __builtin_amdgcn_readlane(way0, src);
            int wb = __builtin_amdgcn_readlane(way1, src);
            int jprev = slot ? wb : wa;
            int pnew;
            if (jprev == 0) pnew = i;
            else {
                int s2 = (jprev - 1) & 63, sl2 = (jprev - 1) >> 6;
                int pa = __builtin_amdgcn_readlane(p0, s2);
                int pb = __builtin_amdgcn_readlane(p1, s2);
                pnew = sl2 ? pb : pa;
            }
            if (c0 == jj) p0 = pnew;
            if (c1 == jj) p1 = pnew;
            jj = jprev;
        }
    }

    unsigned long long m0 = __ballot(p0 != 0);
    unsigned long long m1 = __ballot(p1 != 0);
    int base = b * NT;
    if (p0 != 0) {
        int rank = __popcll(m0 & ((1ull << lane) - 1ull));
        out[base + rank] = c0 - 1;
        out[BATCH * NT + base + rank] = p0 - 1;
    }
    if (p1 != 0) {
        int rank = __popcll(m0) + __popcll(m1 & ((1ull << lane) - 1ull));
        out[base + rank] = c1 - 1;
        out[BATCH * NT + base + rank] = p1 - 1;
    }
}

// -------------------------------------------------------------------------
extern "C" void kernel_launch(void* const* d_in, const int* in_sizes, int n_in,
                              void* d_out, int out_size, void* d_ws, size_t ws_size,
                              hipStream_t stream) {
    const float* logits = (const float*)d_in[0];   // [8,100,81]
    const float* pmasks = (const float*)d_in[1];   // [8,100,256,256]
    const float* tmasks = (const float*)d_in[2];   // [8,32,512,512]
    const int*   labels = (const int*)d_in[3];     // [8,32]

    uint8_t* ws = (uint8_t*)d_ws;
    uint32_t* packed = (uint32_t*)ws;                       // 2 MiB
    uint8_t* zbase = ws + (size_t)BATCH * HWP * 4;
    float* accd = (float*)zbase;                            // 229376 B
    float* accs = (float*)(zbase + 229376);                 // 7168 B  (contiguous with accd)

    int* out = (int*)d_out;   // int32: src [8,32] then tgt [8,32]

    pack_kernel<<<BATCH * HWP / 512, 256, 0, stream>>>(tmasks, packed, accd);
    mfma_kernel<<<dim3(KSPLIT, MTILES, BATCH), 256, 0, stream>>>(pmasks, packed, accd, accs);
    hungarian_kernel<<<BATCH, 64, 0, stream>>>(logits, labels, accd, accs, out);
}

// Round 5
// 569.446 us; speedup vs baseline: 1.0375x; 1.0104x over previous
//
#include <hip/hip_runtime.h>
#include <stdint.h>

// HungarianMatcher on MI355X — round 9: DPP wave-min on the augment chain.
// r8 back-solve: ~100 serial augment iterations; the 6-step ds_bpermute f64
// min butterfly (~300 cyc) dominates each iteration. Replace with:
//   * f32 proxy key reduced via DPP (row_shr 1/2/4/8 + row_bcast 15/31,
//     ~10 cyc/step, result in lane 63) — f64->f32 cvt is monotone, so the
//     true argmin lane is always in the key-min candidate ballot.
//   * exact f64 delta recovered by a wave-uniform loop over candidates
//     (readlane_d; almost always exactly 1) -> delta remains a bit-exact
//     copy of a lane's minv, so the j1 equality-ballot + tie-break from r8
//     are unchanged (identical assignment path).
// pack/mfma unchanged (at their 134/210 MB HBM floors).

#define BATCH 8
#define NQ    100
#define NT    32
#define HWP   65536      // 256*256
#define NCLS  81
#define BIGV  1.0e6
#define MPAD  112        // 7*16
#define MTILES 7
#define KSPLIT 16
#define KC (HWP / KSPLIT)   // 4096 px per block
#define KW (KC / 4)         // 1024 px per wave
#define NITER (KW / 64)     // 16 k-iters of 64 px
#define NZFLOAT 59136       // (2*BATCH*MPAD*32 + 2*BATCH*MPAD) floats

typedef __attribute__((ext_vector_type(8))) short short8;
typedef __attribute__((ext_vector_type(4))) float f32x4;

union FragU { short8 s; uint32_t w[4]; };

__device__ inline uint32_t cvt_pk_bf16(float lo, float hi) {  // RNE packed cvt
    uint32_t r;
    asm("v_cvt_pk_bf16_f32 %0, %1, %2" : "=v"(r) : "v"(lo), "v"(hi));
    return r;
}

// expand bit r (lo halves) / bit r+16 (hi halves) of two packed words into
// two bf16-pair words: value 1.0 (0x3F80) or 0 per half.
__device__ inline void bpair(uint32_t wlo, uint32_t whi, int r,
                             uint32_t& lofrag, uint32_t& hifrag) {
    uint32_t a = wlo >> r;
    uint32_t c = whi >> r;
    uint32_t mlo = (a & 1u) | ((c & 1u) << 16);
    uint32_t mhi = ((a >> 16) & 1u) | (((c >> 16) & 1u) << 16);
    lofrag = (mlo << 14) - (mlo << 7);
    hifrag = (mhi << 14) - (mhi << 7);
}

// push double v to lane tgt across the wave; lanes nobody targets receive 0.
__device__ inline double perm_scatter_d(int tgt, double v) {
    int addr = tgt << 2;
    int lo = __builtin_amdgcn_ds_permute(addr, __double2loint(v));
    int hi = __builtin_amdgcn_ds_permute(addr, __double2hiint(v));
    return __hiloint2double(hi, lo);
}

// uniform-lane gather of a double: 2x v_readlane (SGPR broadcast).
__device__ inline double readlane_d(double v, int lane) {
    int lo = __builtin_amdgcn_readlane(__double2loint(v), lane);
    int hi = __builtin_amdgcn_readlane(__double2hiint(v), lane);
    return __hiloint2double(hi, lo);
}

// one DPP min step: out-of-range source lanes contribute +inf (old value,
// bound_ctrl=0). CTRL is a compile-time DPP control code.
#define DPP_MIN_STEP(v, CTRL)                                                   \
    v = fminf(v, __builtin_bit_cast(float, __builtin_amdgcn_update_dpp(         \
            0x7F800000, __builtin_bit_cast(int, v), (CTRL), 0xF, 0xF, false)))

// wave64 f32 min at VALU speed; result lands in lane 63.
__device__ inline float dpp_wave_min_f32(float v) {
    DPP_MIN_STEP(v, 0x111);   // row_shr:1
    DPP_MIN_STEP(v, 0x112);   // row_shr:2
    DPP_MIN_STEP(v, 0x114);   // row_shr:4
    DPP_MIN_STEP(v, 0x118);   // row_shr:8
    DPP_MIN_STEP(v, 0x142);   // row_bcast:15
    DPP_MIN_STEP(v, 0x143);   // row_bcast:31
    return v;
}

// -------------------------------------------------------------------------
// Pure threshold-copy: 2 output px per thread via one float4 (contiguous
// 16 B/lane), uint2 packed store. Also zeros accd/accs (replaces memset).
__global__ __launch_bounds__(256) void pack_kernel(const float* __restrict__ tmask,
                                                   uint32_t* __restrict__ packed,
                                                   float* __restrict__ zbuf) {
    int idx = blockIdx.x * 256 + threadIdx.x;   // BATCH * HWP/2 threads
    if (idx < NZFLOAT) zbuf[idx] = 0.f;         // fused accumulator clear
    int b  = idx >> 15;                         // 32768 pairs per batch
    int pp = idx & 32767;
    int y  = pp >> 7;                           // out row (in row = 2y)
    int xp = pp & 127;                          // pair: out x = 2xp, 2xp+1
    const float* base = tmask + (size_t)b * NT * 262144 + (size_t)(2 * y) * 512 + 4 * xp;
    uint32_t w0 = 0, w1 = 0;
#pragma unroll
    for (int t = 0; t < NT; ++t) {
        float4 v = *(const float4*)(base + (size_t)t * 262144);
        w0 |= (v.x > 0.5f ? 1u : 0u) << t;
        w1 |= (v.z > 0.5f ? 1u : 0u) << t;
    }
    int p0 = y * 256 + 2 * xp;
    *(uint2*)(packed + (size_t)b * HWP + p0) = make_uint2(w0, w1);
}

// -------------------------------------------------------------------------
// accd: [2][BATCH][MPAD][32] fp32 (dot_pm, dot_sig); accs: [2][BATCH][MPAD]
// Row 100 of the dot_pm accumulator carries the target-mask pixel counts
// (A-row 100 forced to bf16 ones; integer sums < 2^24 -> exact in f32).
__global__ __launch_bounds__(256) void mfma_kernel(const float* __restrict__ pmask,
                                                   const uint32_t* __restrict__ packed,
                                                   float* __restrict__ accd,
                                                   float* __restrict__ accs) {
    const int kblk = blockIdx.x;
    const int mt   = blockIdx.y;
    const int b    = blockIdx.z;
    const int tid  = threadIdx.x;
    const int wv   = tid >> 6, lane = tid & 63;
    const int m0   = mt * 16;
    const int q    = lane >> 4;    // 0..3  (k-quad)
    const int r    = lane & 15;    // 0..15 (A row / B target)

    __shared__ float Cred[8][16][32];

    const bool onesrow = (m0 + r == 100);                  // counts row
    int mrow = m0 + r; if (mrow > NQ - 1) mrow = NQ - 1;   // pad rows dup row 99
    const float* Arow = pmask + (size_t)b * NQ * HWP + (size_t)mrow * HWP;
    const uint32_t* pkb = packed + (size_t)b * HWP;
    const int kbase0 = kblk * KC + wv * KW;

    f32x4 Cpm0 = {0,0,0,0}, Cpm1 = {0,0,0,0}, Csg0 = {0,0,0,0}, Csg1 = {0,0,0,0};
    float rsp = 0.f, rsg = 0.f;

    for (int ki = 0; ki < NITER; ++ki) {
        const int kb = kbase0 + ki * 64;
        // --- direct fragment loads (no LDS) ---
        const float4 va0 = *(const float4*)(Arow + kb + q * 8);
        const float4 va1 = *(const float4*)(Arow + kb + q * 8 + 4);
        const float4 va2 = *(const float4*)(Arow + kb + 32 + q * 8);
        const float4 va3 = *(const float4*)(Arow + kb + 32 + q * 8 + 4);
        const uint4  wb0 = *(const uint4*)(pkb + kb + q * 8);
        const uint4  wb1 = *(const uint4*)(pkb + kb + q * 8 + 4);
        const uint4  wb2 = *(const uint4*)(pkb + kb + 32 + q * 8);
        const uint4  wb3 = *(const uint4*)(pkb + kb + 32 + q * 8 + 4);

        FragU a0, a1, g0, g1;
        auto proc4 = [&](const float4& v, uint32_t* aw, uint32_t* gw) {
            float sg[4];
#pragma unroll
            for (int e = 0; e < 4; ++e) {
                float pv = (&v.x)[e];
                float ax = fabsf(pv);
                float en = __expf(-ax);
                float one_en = 1.0f + en;
                float inv = __builtin_amdgcn_rcpf(one_en);
                float sig = (pv >= 0.f) ? inv : en * inv;
                float sp  = fmaxf(pv, 0.f) + __logf(one_en);
                rsp += sp; rsg += sig;
                sg[e] = sig;
            }
            aw[0] = cvt_pk_bf16(v.x, v.y);
            aw[1] = cvt_pk_bf16(v.z, v.w);
            gw[0] = cvt_pk_bf16(sg[0], sg[1]);
            gw[1] = cvt_pk_bf16(sg[2], sg[3]);
        };
        proc4(va0, &a0.w[0], &g0.w[0]);
        proc4(va1, &a0.w[2], &g0.w[2]);
        proc4(va2, &a1.w[0], &g1.w[0]);
        proc4(va3, &a1.w[2], &g1.w[2]);

        if (onesrow) {   // A-row 100 = bf16 ones -> counts
#pragma unroll
            for (int i2 = 0; i2 < 4; ++i2) { a0.w[i2] = 0x3F803F80u; a1.w[i2] = 0x3F803F80u; }
        }

        FragU b00, b01, b10, b11;
        bpair(wb0.x, wb0.y, r, b00.w[0], b10.w[0]);
        bpair(wb0.z, wb0.w, r, b00.w[1], b10.w[1]);
        bpair(wb1.x, wb1.y, r, b00.w[2], b10.w[2]);
        bpair(wb1.z, wb1.w, r, b00.w[3], b10.w[3]);
        bpair(wb2.x, wb2.y, r, b01.w[0], b11.w[0]);
        bpair(wb2.z, wb2.w, r, b01.w[1], b11.w[1]);
        bpair(wb3.x, wb3.y, r, b01.w[2], b11.w[2]);
        bpair(wb3.z, wb3.w, r, b01.w[3], b11.w[3]);

        Cpm0 = __builtin_amdgcn_mfma_f32_16x16x32_bf16(a0.s, b00.s, Cpm0, 0, 0, 0);
        Cpm0 = __builtin_amdgcn_mfma_f32_16x16x32_bf16(a1.s, b01.s, Cpm0, 0, 0, 0);
        Cpm1 = __builtin_amdgcn_mfma_f32_16x16x32_bf16(a0.s, b10.s, Cpm1, 0, 0, 0);
        Cpm1 = __builtin_amdgcn_mfma_f32_16x16x32_bf16(a1.s, b11.s, Cpm1, 0, 0, 0);
        Csg0 = __builtin_amdgcn_mfma_f32_16x16x32_bf16(g0.s, b00.s, Csg0, 0, 0, 0);
        Csg0 = __builtin_amdgcn_mfma_f32_16x16x32_bf16(g1.s, b01.s, Csg0, 0, 0, 0);
        Csg1 = __builtin_amdgcn_mfma_f32_16x16x32_bf16(g0.s, b10.s, Csg1, 0, 0, 0);
        Csg1 = __builtin_amdgcn_mfma_f32_16x16x32_bf16(g1.s, b11.s, Csg1, 0, 0, 0);
    }

    // row sums: reduce across the 4 k-quads (lane bits 4,5) -> q==0 lanes
    rsp += __shfl_xor(rsp, 16, 64);
    rsp += __shfl_xor(rsp, 32, 64);
    rsg += __shfl_xor(rsg, 16, 64);
    rsg += __shfl_xor(rsg, 32, 64);
    if (q == 0 && m0 + r < NQ) {
        atomicAdd(&accs[(size_t)b * MPAD + m0 + r], rsp);
        atomicAdd(&accs[(size_t)(BATCH + b) * MPAD + m0 + r], rsg);
    }

    // C/D layout: col = lane&15 (target), row = (lane>>4)*4 + e (query)
#pragma unroll
    for (int e = 0; e < 4; ++e) {
        const int m = q * 4 + e;
        Cred[wv * 2 + 0][m][r]      = Cpm0[e];
        Cred[wv * 2 + 0][m][16 + r] = Cpm1[e];
        Cred[wv * 2 + 1][m][r]      = Csg0[e];
        Cred[wv * 2 + 1][m][16 + r] = Csg1[e];
    }
    __syncthreads();
    for (int idx = tid; idx < 1024; idx += 256) {
        const int type = idx >> 9, rem = idx & 511, m = rem >> 5, n = rem & 31;
        float s = Cred[0 + type][m][n] + Cred[2 + type][m][n]
                + Cred[4 + type][m][n] + Cred[6 + type][m][n];
        const int gm = m0 + m;
        if (gm < 101)   // rows 0..99 = queries, row 100 = tm counts
            atomicAdd(&accd[(size_t)(type * BATCH + b) * MPAD * 32 + (size_t)gm * 32 + n], s);
    }
}

// -------------------------------------------------------------------------
// Finalize cost matrix + exact single-wave JV Hungarian.
// Register u[], readlane gathers, DPP proxy-min + exact f64 refine.
__global__ __launch_bounds__(64) void hungarian_kernel(const float* __restrict__ logits,
                                                       const int* __restrict__ labels,
                                                       const float* __restrict__ accd,
                                                       const float* __restrict__ accs,
                                                       int* __restrict__ out) {
    const int b = blockIdx.x;
    const int lane = threadIdx.x;

    __shared__ double Ct[NT][128];          // cols 100..127 = dummy (1e30)
    __shared__ float smx[NQ], ssm[NQ];
    __shared__ float tcs[NT];
    __shared__ int lab[NT];

    if (lane < NT) {
        tcs[lane] = accd[(size_t)b * MPAD * 32 + 100 * 32 + lane];  // MFMA-computed counts
        lab[lane] = labels[b * NT + lane];
    }
    for (int n = lane; n < NQ; n += 64) {
        const float* lg = logits + (size_t)(b * NQ + n) * NCLS;
        float mx = -1e30f;
        for (int c = 0; c < NCLS; ++c) mx = fmaxf(mx, lg[c]);
        float s = 0.f;
        for (int c = 0; c < NCLS; ++c) s += __expf(lg[c] - mx);
        smx[n] = mx; ssm[n] = s;
    }
    __syncthreads();
    for (int idx = lane; idx < NT * 128; idx += 64) {
        const int t2 = idx >> 7, q2 = idx & 127;
        if (q2 < NQ) {
            float dpm = accd[(size_t)b * MPAD * 32 + q2 * 32 + t2];
            float dsg = accd[(size_t)(BATCH + b) * MPAD * 32 + q2 * 32 + t2];
            float ssp = accs[(size_t)b * MPAD + q2];
            float ssg = accs[(size_t)(BATCH + b) * MPAD + q2];
            float lg = logits[(size_t)(b * NQ + q2) * NCLS + lab[t2]];
            float prob = __expf(lg - smx[q2]) / ssm[q2];
            float c = -prob + (ssp - dpm) * (1.0f / (float)HWP)
                    + 1.0f - (2.0f * dsg + 1.0f) / (ssg + tcs[t2] + 1.0f);
            if (isnan(c)) c = (float)BIGV;
            else if (isinf(c)) c = (c > 0.f) ? (float)BIGV : -(float)BIGV;
            Ct[t2][q2] = (double)c;
        } else {
            Ct[t2][q2] = 1.0e30;            // dummy col: never wins the min
        }
    }
    __syncthreads();

    const int c0 = lane + 1;                // JV col ids (1-based)
    const int c1 = lane + 65;               // 65..128 (101..128 are dummies)

    double v0 = 0.0, v1 = 0.0;
    int p0 = 0, p1 = 0;
    double u_reg = 0.0;                     // lane L owns u[L]; lane 63 = trash sink

    for (int i = 1; i <= NT; ++i) {
        double minv0 = 1e300, minv1 = 1e300;
        int way0 = 0, way1 = 0;
        bool used0 = false, used1 = false;
        double du0 = 0.0, du1 = 0.0, dtot = 0.0;
        int j0 = 0, i0 = i;
        int jfin = 0;

        for (int guard = 0; guard < 160; ++guard) {
            double u_i0 = readlane_d(u_reg, i0);     // uniform gather
            const double* ctrow = &Ct[i0 - 1][0];
            double cur0 = ctrow[lane]      - u_i0 - v0;
            double cur1 = ctrow[lane + 64] - u_i0 - v1;
            if (!used0 && cur0 < minv0) { minv0 = cur0; way0 = j0; }
            if (!used1 && cur1 < minv1) { minv1 = cur1; way1 = j0; }
            // per-lane candidate: best unused col in this lane's two slots
            double bv = used0 ? 1e301 : minv0;
            if (!used1 && minv1 < bv) bv = minv1;
            // DPP proxy min (f64->f32 cvt is monotone): candidate set via
            // ballot, then exact f64 delta by readlane over candidates.
            float kf = (float)bv;
            float kred = dpp_wave_min_f32(kf);
            float kmin = __builtin_bit_cast(float,
                __builtin_amdgcn_readlane(__builtin_bit_cast(int, kred), 63));
            unsigned long long cand = __ballot(kf == kmin);
            double delta = 1e301;
            do {                                      // wave-uniform; ~1 pass
                int l = __ffsll(cand) - 1;
                double dv = readlane_d(bv, l);
                delta = fmin(delta, dv);
                cand &= cand - 1;
            } while (cand);
            // argmin col via exact equality ballot (delta is a bit-exact copy
            // of some lane's minv); slot0 cols < slot1 cols, ffs = smallest.
            unsigned long long e0 = __ballot(!used0 && minv0 == delta);
            unsigned long long e1 = __ballot(!used1 && minv1 == delta);
            int j1 = e0 ? __ffsll((unsigned long long)e0)
                        : (64 + __ffsll((unsigned long long)e1));
            dtot += delta;
            if (used0) { v0 -= delta; du0 += delta; } else { minv0 -= delta; }
            if (used1) { v1 -= delta; du1 += delta; } else { minv1 -= delta; }
            if (c0 == j1) used0 = true;
            if (c1 == j1) used1 = true;
            int src = (j1 - 1) & 63, slot = (j1 - 1) >> 6;
            int pa = __builtin_amdgcn_readlane(p0, src);
            int pb = __builtin_amdgcn_readlane(p1, src);
            int pj1 = slot ? pb : pa;
            if (pj1 == 0) { jfin = j1; break; }
            j0 = j1; i0 = pj1;
        }

        // deferred u updates: scatter du to owning lanes (distinct rows across
        // used cols -> collision-free; lane 63 takes the discards).
        int t0 = (used0 && p0 != 0) ? p0 : 63;
        int t1 = (used1 && p1 != 0) ? p1 : 63;
        u_reg += perm_scatter_d(t0, du0) + perm_scatter_d(t1, du1);
        if (lane == i) u_reg += dtot;       // dtot is wave-uniform

        int jj = jfin;
        for (int guard = 0; guard < 160 && jj != 0; ++guard) {
            int src = (jj - 1) & 63, slot = (jj - 1) >> 6;
            int wa = __builtin_amdgcn_readlane(way0, src);
            int wb = __builtin_amdgcn_readlane(way1, src);
            int jprev = slot ? wb : wa;
            int pnew;
            if (jprev == 0) pnew = i;
            else {
                int s2 = (jprev - 1) & 63, sl2 = (jprev - 1) >> 6;
                int pa = __builtin_amdgcn_readlane(p0, s2);
                int pb = __builtin_amdgcn_readlane(p1, s2);
                pnew = sl2 ? pb : pa;
            }
            if (c0 == jj) p0 = pnew;
            if (c1 == jj) p1 = pnew;
            jj = jprev;
        }
    }

    unsigned long long m0 = __ballot(p0 != 0);
    unsigned long long m1 = __ballot(p1 != 0);
    int base = b * NT;
    if (p0 != 0) {
        int rank = __popcll(m0 & ((1ull << lane) - 1ull));
        out[base + rank] = c0 - 1;
        out[BATCH * NT + base + rank] = p0 - 1;
    }
    if (p1 != 0) {
        int rank = __popcll(m0) + __popcll(m1 & ((1ull << lane) - 1ull));
        out[base + rank] = c1 - 1;
        out[BATCH * NT + base + rank] = p1 - 1;
    }
}

// -------------------------------------------------------------------------
extern "C" void kernel_launch(void* const* d_in, const int* in_sizes, int n_in,
                              void* d_out, int out_size, void* d_ws, size_t ws_size,
                              hipStream_t stream) {
    const float* logits = (const float*)d_in[0];   // [8,100,81]
    const float* pmasks = (const float*)d_in[1];   // [8,100,256,256]
    const float* tmasks = (const float*)d_in[2];   // [8,32,512,512]
    const int*   labels = (const int*)d_in[3];     // [8,32]

    uint8_t* ws = (uint8_t*)d_ws;
    uint32_t* packed = (uint32_t*)ws;                       // 2 MiB
    uint8_t* zbase = ws + (size_t)BATCH * HWP * 4;
    float* accd = (float*)zbase;                            // 229376 B
    float* accs = (float*)(zbase + 229376);                 // 7168 B  (contiguous with accd)

    int* out = (int*)d_out;   // int32: src [8,32] then tgt [8,32]

    pack_kernel<<<BATCH * HWP / 512, 256, 0, stream>>>(tmasks, packed, accd);
    mfma_kernel<<<dim3(KSPLIT, MTILES, BATCH), 256, 0, stream>>>(pmasks, packed, accd, accs);
    hungarian_kernel<<<BATCH, 64, 0, stream>>>(logits, labels, accd, accs, out);
}